// Round 1
// baseline (375.954 us; speedup 1.0000x reference)
//
#include <hip/hip_runtime.h>
#include <hip/hip_bf16.h>

typedef __hip_bfloat16 bf16;
typedef __attribute__((ext_vector_type(8))) short bf16x8;
typedef __attribute__((ext_vector_type(4))) float f32x4;

#define GLD16(gp, lp) __builtin_amdgcn_global_load_lds( \
    (const __attribute__((address_space(1))) void*)(gp), \
    (__attribute__((address_space(3))) void*)(lp), 16, 0, 0)

// ---------------------------------------------------------------------------
// fp32 -> bf16 convert, 4 elems/thread, exact grid (n divisible by 1024)
// ---------------------------------------------------------------------------
__global__ __launch_bounds__(256) void cvt_bf16(const float* __restrict__ in,
                                                bf16* __restrict__ out) {
    int i = (blockIdx.x * 256 + threadIdx.x) * 4;
    float4 f = *(const float4*)&in[i];
    __hip_bfloat162 p0, p1;
    p0.x = __float2bfloat16(f.x); p0.y = __float2bfloat16(f.y);
    p1.x = __float2bfloat16(f.z); p1.y = __float2bfloat16(f.w);
    *(__hip_bfloat162*)&out[i]     = p0;
    *(__hip_bfloat162*)&out[i + 2] = p1;
}

// ---------------------------------------------------------------------------
// V [B*T][1024] -> Vt [B][1024][T]  (32x32 LDS tile transpose)
// grid (1024/32, T/32, B), block (32,8)
// ---------------------------------------------------------------------------
__global__ void transpose_v(const bf16* __restrict__ V, bf16* __restrict__ Vt) {
    __shared__ bf16 tile[32][33];
    const int b = blockIdx.z;
    const int c0 = blockIdx.x * 32, t0 = blockIdx.y * 32;
    const int tx = threadIdx.x, ty = threadIdx.y;
    #pragma unroll
    for (int i = 0; i < 32; i += 8)
        tile[ty + i][tx] = V[((size_t)(b * 2048 + t0 + ty + i)) * 1024 + c0 + tx];
    __syncthreads();
    #pragma unroll
    for (int i = 0; i < 32; i += 8)
        Vt[((size_t)b * 1024 + c0 + ty + i) * 2048 + t0 + tx] = tile[tx][ty + i];
}

// ---------------------------------------------------------------------------
// Causal row softmax over S (fp32 [8192][2048]); writes bf16 P in place at the
// start of each S row (row stride 4096 bf16 elems). Zeros above diagonal.
// grid 8192 x block 256, 8 elems/thread.
// ---------------------------------------------------------------------------
__global__ __launch_bounds__(256) void softmax_causal(float* __restrict__ S) {
    const int row = blockIdx.x;
    const int t = row & 2047;
    float* srow = S + (size_t)row * 2048;
    bf16* prow = (bf16*)srow;
    const int tid = threadIdx.x;
    const int base = tid * 8;
    float4 f0 = *(const float4*)&srow[base];
    float4 f1 = *(const float4*)&srow[base + 4];
    float v[8] = {f0.x, f0.y, f0.z, f0.w, f1.x, f1.y, f1.z, f1.w};
    float lmax = -INFINITY;
    #pragma unroll
    for (int i = 0; i < 8; ++i) {
        v[i] = (base + i <= t) ? v[i] : -INFINITY;
        lmax = fmaxf(lmax, v[i]);
    }
    #pragma unroll
    for (int off = 32; off; off >>= 1) lmax = fmaxf(lmax, __shfl_xor(lmax, off));
    __shared__ float red[4];
    const int wave = tid >> 6, lane = tid & 63;
    if (lane == 0) red[wave] = lmax;
    __syncthreads();
    lmax = fmaxf(fmaxf(red[0], red[1]), fmaxf(red[2], red[3]));
    float lsum = 0.f;
    #pragma unroll
    for (int i = 0; i < 8; ++i) { v[i] = __expf(v[i] - lmax); lsum += v[i]; }
    #pragma unroll
    for (int off = 32; off; off >>= 1) lsum += __shfl_xor(lsum, off);
    __syncthreads();
    if (lane == 0) red[wave] = lsum;
    __syncthreads();
    lsum = red[0] + red[1] + red[2] + red[3];
    const float inv = 1.f / lsum;
    #pragma unroll
    for (int i = 0; i < 8; ++i) prow[base + i] = __float2bfloat16(v[i] * inv);
}

// ---------------------------------------------------------------------------
// Generic 128x128-tile bf16 GEMM, C = A * B^T (B stored [N][K]) + epilogue.
// 4 waves, each owns a 64x64 sub-tile (4x4 fragments of 16x16x32 MFMA).
// modes: 0 = QKV (+bias, route to Q/K/V bf16)
//        1 = scores (scale 1/32, fp32 out, skip blocks above diagonal)
//        2 = PV (bf16 out, K-loop clipped to causal extent)
//        3 = proj (+bias, fp32 out)
// ---------------------------------------------------------------------------
__global__ __launch_bounds__(256) void gemm_bt(
    int mode,
    const bf16* __restrict__ A, int lda, size_t batchA,
    const bf16* __restrict__ B, int ldb, size_t batchB,
    int K,
    const float* __restrict__ bias,
    void* __restrict__ out0, void* __restrict__ out1, void* __restrict__ out2)
{
    constexpr int BK = 32;
    __shared__ bf16 As[128][BK];
    __shared__ bf16 Bs[128][BK];

    const int bx = blockIdx.x, by = blockIdx.y, bz = blockIdx.z;
    if (mode == 1 && bx > by) return;   // fully-masked score block
    const int m0 = by * 128, n0 = bx * 128;
    const int keff = (mode == 2) ? (by + 1) * 128 : K;

    const bf16* Ab = A + (size_t)bz * batchA;
    const bf16* Bb = B + (size_t)bz * batchB;

    const int tid = threadIdx.x;
    const int lane = tid & 63;
    const int wave = tid >> 6;
    const int wm = (wave >> 1) * 64;
    const int wn = (wave & 1) * 64;

    f32x4 acc[4][4] = {};

    for (int k0 = 0; k0 < keff; k0 += BK) {
        #pragma unroll
        for (int p = 0; p < 2; ++p) {
            int idx = p * 256 + tid;
            int r = idx >> 2;
            int kc = (idx & 3) * 8;
            GLD16(Ab + (size_t)(m0 + r) * lda + (k0 + kc), &As[r][kc]);
            GLD16(Bb + (size_t)(n0 + r) * ldb + (k0 + kc), &Bs[r][kc]);
        }
        __syncthreads();   // compiler emits vmcnt(0) drain before barrier

        bf16x8 af[4], bfr[4];
        #pragma unroll
        for (int m = 0; m < 4; ++m)
            af[m] = *(const bf16x8*)&As[wm + m * 16 + (lane & 15)][(lane >> 4) * 8];
        #pragma unroll
        for (int n = 0; n < 4; ++n)
            bfr[n] = *(const bf16x8*)&Bs[wn + n * 16 + (lane & 15)][(lane >> 4) * 8];
        #pragma unroll
        for (int m = 0; m < 4; ++m)
            #pragma unroll
            for (int n = 0; n < 4; ++n)
                acc[m][n] = __builtin_amdgcn_mfma_f32_16x16x32_bf16(
                    af[m], bfr[n], acc[m][n], 0, 0, 0);
        __syncthreads();
    }

    // epilogue: C/D layout col = lane&15, row = (lane>>4)*4 + reg  [m89]
    #pragma unroll
    for (int m = 0; m < 4; ++m) {
        #pragma unroll
        for (int n = 0; n < 4; ++n) {
            #pragma unroll
            for (int j = 0; j < 4; ++j) {
                const int gr = m0 + wm + m * 16 + ((lane >> 4) << 2) + j;
                const int gc = n0 + wn + n * 16 + (lane & 15);
                float v = acc[m][n][j];
                if (mode == 0) {
                    v += bias[gc];
                    const int which = gc >> 10;
                    const int col = gc & 1023;
                    bf16* dst = which == 0 ? (bf16*)out0
                              : which == 1 ? (bf16*)out1 : (bf16*)out2;
                    dst[(size_t)gr * 1024 + col] = __float2bfloat16(v);
                } else if (mode == 1) {
                    ((float*)out0)[(size_t)bz * (2048ull * 2048) +
                                   (size_t)gr * 2048 + gc] = v * 0.03125f;
                } else if (mode == 2) {
                    ((bf16*)out0)[((size_t)bz * 2048 + gr) * 1024 + gc] =
                        __float2bfloat16(v);
                } else {
                    ((float*)out0)[(size_t)gr * 1024 + gc] = v + bias[gc];
                }
            }
        }
    }
}

// ---------------------------------------------------------------------------
extern "C" void kernel_launch(void* const* d_in, const int* in_sizes, int n_in,
                              void* d_out, int out_size, void* d_ws, size_t ws_size,
                              hipStream_t stream) {
    const float* x      = (const float*)d_in[0];
    const float* w_qkv  = (const float*)d_in[1];
    const float* b_qkv  = (const float*)d_in[2];
    const float* w_proj = (const float*)d_in[3];
    const float* b_proj = (const float*)d_in[4];
    float* out = (float*)d_out;
    char* ws = (char*)d_ws;

    // workspace layout (bytes)
    bf16* Xb = (bf16*)(ws);                        // 16,777,216   (later: Vt)
    bf16* Wq = (bf16*)(ws + 16777216);             //  6,291,456
    bf16* Wp = (bf16*)(ws + 23068672);             //  2,097,152
    bf16* Qb = (bf16*)(ws + 25165824);             // 16,777,216   (later: O)
    bf16* Kb = (bf16*)(ws + 41943040);             // 16,777,216
    bf16* Vb = (bf16*)(ws + 58720256);             // 16,777,216
    float* S = (float*)(ws + 75497472);            // 67,108,864  (P in-place)
    bf16* Vt = Xb;
    bf16* O  = Qb;

    // converts
    hipLaunchKernelGGL(cvt_bf16, dim3(8192), dim3(256), 0, stream, x, Xb);
    hipLaunchKernelGGL(cvt_bf16, dim3(3072), dim3(256), 0, stream, w_qkv, Wq);
    hipLaunchKernelGGL(cvt_bf16, dim3(1024), dim3(256), 0, stream, w_proj, Wp);

    // QKV = Xb * Wq^T + b_qkv   -> Q,K,V bf16
    hipLaunchKernelGGL(gemm_bt, dim3(24, 64, 1), dim3(256), 0, stream,
        0, Xb, 1024, (size_t)0, Wq, 1024, (size_t)0, 1024, b_qkv,
        (void*)Qb, (void*)Kb, (void*)Vb);

    // Vt[b][c][t] = V[b][t][c]
    hipLaunchKernelGGL(transpose_v, dim3(32, 64, 4), dim3(32, 8), 0, stream, Vb, Vt);

    // S = Q * K^T / 32  (lower-triangle blocks only)
    hipLaunchKernelGGL(gemm_bt, dim3(16, 16, 4), dim3(256), 0, stream,
        1, Qb, 1024, (size_t)(2048ull * 1024), Kb, 1024, (size_t)(2048ull * 1024),
        1024, (const float*)nullptr, (void*)S, (void*)nullptr, (void*)nullptr);

    // causal softmax, P (bf16) in place over S rows
    hipLaunchKernelGGL(softmax_causal, dim3(8192), dim3(256), 0, stream, S);

    // O = P * V   (A = P with lda 4096, B = Vt, causal K clip)
    hipLaunchKernelGGL(gemm_bt, dim3(8, 16, 4), dim3(256), 0, stream,
        2, (const bf16*)S, 4096, (size_t)(2048ull * 4096), Vt, 2048,
        (size_t)(1024ull * 2048), 2048, (const float*)nullptr,
        (void*)O, (void*)nullptr, (void*)nullptr);

    // out = O * Wp^T + b_proj  (fp32)
    hipLaunchKernelGGL(gemm_bt, dim3(8, 64, 1), dim3(256), 0, stream,
        3, O, 1024, (size_t)0, Wp, 1024, (size_t)0, 1024, b_proj,
        (void*)out, (void*)nullptr, (void*)nullptr);
}

// Round 2
// 339.055 us; speedup vs baseline: 1.1088x; 1.1088x over previous
//
#include <hip/hip_runtime.h>
#include <hip/hip_bf16.h>

typedef __hip_bfloat16 bf16;
typedef __attribute__((ext_vector_type(8))) short bf16x8;
typedef __attribute__((ext_vector_type(4))) float f32x4;

#define GLD16(gp, lp) __builtin_amdgcn_global_load_lds( \
    (const __attribute__((address_space(1))) void*)(gp), \
    (__attribute__((address_space(3))) void*)(lp), 16, 0, 0)

// ---------------------------------------------------------------------------
// fp32 -> bf16 convert, 4 elems/thread
// ---------------------------------------------------------------------------
__global__ __launch_bounds__(256) void cvt_bf16(const float* __restrict__ in,
                                                bf16* __restrict__ out) {
    int i = (blockIdx.x * 256 + threadIdx.x) * 4;
    float4 f = *(const float4*)&in[i];
    __hip_bfloat162 p0, p1;
    p0.x = __float2bfloat16(f.x); p0.y = __float2bfloat16(f.y);
    p1.x = __float2bfloat16(f.z); p1.y = __float2bfloat16(f.w);
    *(__hip_bfloat162*)&out[i]     = p0;
    *(__hip_bfloat162*)&out[i + 2] = p1;
}

// ---------------------------------------------------------------------------
// V [B*T][1024] -> Vt [B][1024][T]
// ---------------------------------------------------------------------------
__global__ void transpose_v(const bf16* __restrict__ V, bf16* __restrict__ Vt) {
    __shared__ bf16 tile[32][33];
    const int b = blockIdx.z;
    const int c0 = blockIdx.x * 32, t0 = blockIdx.y * 32;
    const int tx = threadIdx.x, ty = threadIdx.y;
    #pragma unroll
    for (int i = 0; i < 32; i += 8)
        tile[ty + i][tx] = V[((size_t)(b * 2048 + t0 + ty + i)) * 1024 + c0 + tx];
    __syncthreads();
    #pragma unroll
    for (int i = 0; i < 32; i += 8)
        Vt[((size_t)b * 1024 + c0 + ty + i) * 2048 + t0 + tx] = tile[tx][ty + i];
}

// ---------------------------------------------------------------------------
// Causal row softmax over S fp32 [8192][2048]; writes bf16 P in place.
// ---------------------------------------------------------------------------
__global__ __launch_bounds__(256) void softmax_causal(float* __restrict__ S) {
    const int row = blockIdx.x;
    const int t = row & 2047;
    float* srow = S + (size_t)row * 2048;
    bf16* prow = (bf16*)srow;
    const int tid = threadIdx.x;
    const int base = tid * 8;
    float4 f0 = *(const float4*)&srow[base];
    float4 f1 = *(const float4*)&srow[base + 4];
    float v[8] = {f0.x, f0.y, f0.z, f0.w, f1.x, f1.y, f1.z, f1.w};
    float lmax = -INFINITY;
    #pragma unroll
    for (int i = 0; i < 8; ++i) {
        v[i] = (base + i <= t) ? v[i] : -INFINITY;
        lmax = fmaxf(lmax, v[i]);
    }
    #pragma unroll
    for (int off = 32; off; off >>= 1) lmax = fmaxf(lmax, __shfl_xor(lmax, off));
    __shared__ float red[4];
    const int wave = tid >> 6, lane = tid & 63;
    if (lane == 0) red[wave] = lmax;
    __syncthreads();
    lmax = fmaxf(fmaxf(red[0], red[1]), fmaxf(red[2], red[3]));
    float lsum = 0.f;
    #pragma unroll
    for (int i = 0; i < 8; ++i) { v[i] = __expf(v[i] - lmax); lsum += v[i]; }
    #pragma unroll
    for (int off = 32; off; off >>= 1) lsum += __shfl_xor(lsum, off);
    __syncthreads();
    if (lane == 0) red[wave] = lsum;
    __syncthreads();
    lsum = red[0] + red[1] + red[2] + red[3];
    const float inv = 1.f / lsum;
    #pragma unroll
    for (int i = 0; i < 8; ++i) prow[base + i] = __float2bfloat16(v[i] * inv);
}

// ---------------------------------------------------------------------------
// 128x128-tile bf16 GEMM (kept for PV, mode 2: causal K clip, bf16 out)
// ---------------------------------------------------------------------------
__global__ __launch_bounds__(256) void gemm_bt(
    int mode,
    const bf16* __restrict__ A, int lda, size_t batchA,
    const bf16* __restrict__ B, int ldb, size_t batchB,
    int K,
    const float* __restrict__ bias,
    void* __restrict__ out0, void* __restrict__ out1, void* __restrict__ out2)
{
    constexpr int BK = 32;
    __shared__ bf16 As[128][BK];
    __shared__ bf16 Bs[128][BK];

    const int bx = blockIdx.x, by = blockIdx.y, bz = blockIdx.z;
    if (mode == 1 && bx > by) return;
    const int m0 = by * 128, n0 = bx * 128;
    const int keff = (mode == 2) ? (by + 1) * 128 : K;

    const bf16* Ab = A + (size_t)bz * batchA;
    const bf16* Bb = B + (size_t)bz * batchB;

    const int tid = threadIdx.x;
    const int lane = tid & 63;
    const int wave = tid >> 6;
    const int wm = (wave >> 1) * 64;
    const int wn = (wave & 1) * 64;

    f32x4 acc[4][4] = {};

    for (int k0 = 0; k0 < keff; k0 += BK) {
        #pragma unroll
        for (int p = 0; p < 2; ++p) {
            int idx = p * 256 + tid;
            int r = idx >> 2;
            int kc = (idx & 3) * 8;
            GLD16(Ab + (size_t)(m0 + r) * lda + (k0 + kc), &As[r][kc]);
            GLD16(Bb + (size_t)(n0 + r) * ldb + (k0 + kc), &Bs[r][kc]);
        }
        __syncthreads();

        bf16x8 af[4], bfr[4];
        #pragma unroll
        for (int m = 0; m < 4; ++m)
            af[m] = *(const bf16x8*)&As[wm + m * 16 + (lane & 15)][(lane >> 4) * 8];
        #pragma unroll
        for (int n = 0; n < 4; ++n)
            bfr[n] = *(const bf16x8*)&Bs[wn + n * 16 + (lane & 15)][(lane >> 4) * 8];
        #pragma unroll
        for (int m = 0; m < 4; ++m)
            #pragma unroll
            for (int n = 0; n < 4; ++n)
                acc[m][n] = __builtin_amdgcn_mfma_f32_16x16x32_bf16(
                    af[m], bfr[n], acc[m][n], 0, 0, 0);
        __syncthreads();
    }

    #pragma unroll
    for (int m = 0; m < 4; ++m) {
        #pragma unroll
        for (int n = 0; n < 4; ++n) {
            #pragma unroll
            for (int j = 0; j < 4; ++j) {
                const int gr = m0 + wm + m * 16 + ((lane >> 4) << 2) + j;
                const int gc = n0 + wn + n * 16 + (lane & 15);
                float v = acc[m][n][j];
                if (mode == 0) {
                    v += bias[gc];
                    const int which = gc >> 10;
                    const int col = gc & 1023;
                    bf16* dst = which == 0 ? (bf16*)out0
                              : which == 1 ? (bf16*)out1 : (bf16*)out2;
                    dst[(size_t)gr * 1024 + col] = __float2bfloat16(v);
                } else if (mode == 1) {
                    ((float*)out0)[(size_t)bz * (2048ull * 2048) +
                                   (size_t)gr * 2048 + gc] = v * 0.03125f;
                } else if (mode == 2) {
                    ((bf16*)out0)[((size_t)bz * 2048 + gr) * 1024 + gc] =
                        __float2bfloat16(v);
                } else {
                    ((float*)out0)[(size_t)gr * 1024 + gc] = v + bias[gc];
                }
            }
        }
    }
}

// ---------------------------------------------------------------------------
// 256x256-tile 8-phase bf16 GEMM, C = A * B^T, K = 1024 fixed (NT=16).
// 512 threads = 8 waves (2M x 4N). Per phase q: wave piece is the 64x32 block
// at rows (q>>1)*128 + wr*64, cols (q&1)*128 + wc*32 -> quadrant-aligned so
// phase q of tile t only reads A-half (q>>1), B-half (q&1).
// Half-tile issue order for tile t+1 during tile t: A0@q0, B0@q1, B1@q2, A1@q3.
// Steady-state wait vmcnt(6) at q0,q1,q2; last tile drains 4->2->0.
// LDS swizzle: slot ^= row&7 (16B slots within 128B row), applied on the
// global SOURCE address (linear gload_lds dest) and on the ds_read address.
// MODE: 0 = QKV (+bias, split to 3 bf16 outs), 1 = scores (fp32, *1/32,
// triangle skip), 3 = proj (fp32 +bias).
// ---------------------------------------------------------------------------
template<int MODE>
__global__ __launch_bounds__(512, 2) void gemm256(
    const bf16* __restrict__ A, const bf16* __restrict__ B,
    const float* __restrict__ bias,
    void* __restrict__ out0, void* __restrict__ out1, void* __restrict__ out2)
{
    __shared__ bf16 As[2][256][64];
    __shared__ bf16 Bs[2][256][64];
    constexpr int NT = 16;   // K = 1024

    const int bx = blockIdx.x, by = blockIdx.y, bz = blockIdx.z;
    if (MODE == 1 && bx > by) return;
    const int m0 = by * 256, n0 = bx * 256;

    const bf16* Ab = A + (MODE == 1 ? (size_t)bz * (2048ull * 1024) : 0);
    const bf16* Bb = B + (MODE == 1 ? (size_t)bz * (2048ull * 1024) : 0);

    const int tid = threadIdx.x;
    const int lane = tid & 63, wave = tid >> 6;
    const int wr = wave >> 2, wc = wave & 3;
    const int frow = lane & 15, fk = lane >> 4, fx = lane & 7;

    // staging constants: thread stages 16B chunk (row = tid>>3 (+64 for j=1),
    // dest slot = tid&7); source slot = dest ^ (row&7)  [inverse swizzle]
    const int rl = tid >> 3;
    const int scol = ((tid & 7) ^ (rl & 7)) * 8;
    const bf16* pAsrc = Ab + (size_t)(m0 + rl) * 1024 + scol;
    const bf16* pBsrc = Bb + (size_t)(n0 + rl) * 1024 + scol;
    const int dchunk = tid * 8;   // LDS elem offset of j=0 chunk

    f32x4 acc[4][4][2] = {};

    #define STG(P, LDSBASE, H, K0) do { \
        GLD16((P) + (size_t)(H) * 128 * 1024 + (K0), (LDSBASE) + (H) * 8192 + dchunk); \
        GLD16((P) + (size_t)((H) * 128 + 64) * 1024 + (K0), (LDSBASE) + (H) * 8192 + 4096 + dchunk); \
    } while (0)

    // prologue: tile 0 -> buffer 0, order A0, B0, B1, A1
    {
        bf16* la = &As[0][0][0]; bf16* lb = &Bs[0][0][0];
        STG(pAsrc, la, 0, 0);
        STG(pBsrc, lb, 0, 0);
        STG(pBsrc, lb, 1, 0);
        STG(pAsrc, la, 1, 0);
    }

    for (int t = 0; t < NT; ++t) {
        const int buf = t & 1, nbuf = buf ^ 1;
        const int kn = (t + 1) * 64;
        bf16* lan = &As[nbuf][0][0]; bf16* lbn = &Bs[nbuf][0][0];
        const bool more = (t + 1 < NT);

        #pragma unroll
        for (int q = 0; q < 4; ++q) {
            if (more) {
                if (q == 0)      STG(pAsrc, lan, 0, kn);
                else if (q == 1) STG(pBsrc, lbn, 0, kn);
                else if (q == 2) STG(pBsrc, lbn, 1, kn);
                else             STG(pAsrc, lan, 1, kn);
                if (q < 3) asm volatile("s_waitcnt vmcnt(6)" ::: "memory");
            } else {
                if (q == 0)      asm volatile("s_waitcnt vmcnt(4)" ::: "memory");
                else if (q == 1) asm volatile("s_waitcnt vmcnt(2)" ::: "memory");
                else if (q == 2) asm volatile("s_waitcnt vmcnt(0)" ::: "memory");
            }
            __builtin_amdgcn_s_barrier();

            const int aR = ((q >> 1) << 7) + wr * 64 + frow;
            const int bR = ((q & 1) << 7) + wc * 32 + frow;
            bf16x8 av[4][2], bv[2][2];
            #pragma unroll
            for (int m = 0; m < 4; ++m)
                #pragma unroll
                for (int ks = 0; ks < 2; ++ks)
                    av[m][ks] = *(const bf16x8*)
                        &As[buf][aR + m * 16][((((ks << 2) | fk) ^ fx) << 3)];
            #pragma unroll
            for (int n = 0; n < 2; ++n)
                #pragma unroll
                for (int ks = 0; ks < 2; ++ks)
                    bv[n][ks] = *(const bf16x8*)
                        &Bs[buf][bR + n * 16][((((ks << 2) | fk) ^ fx) << 3)];

            __builtin_amdgcn_s_setprio(1);
            #pragma unroll
            for (int m = 0; m < 4; ++m)
                #pragma unroll
                for (int n = 0; n < 2; ++n)
                    #pragma unroll
                    for (int ks = 0; ks < 2; ++ks)
                        acc[q][m][n] = __builtin_amdgcn_mfma_f32_16x16x32_bf16(
                            av[m][ks], bv[n][ks], acc[q][m][n], 0, 0, 0);
            __builtin_amdgcn_s_setprio(0);
        }
    }
    #undef STG

    // epilogue
    #pragma unroll
    for (int q = 0; q < 4; ++q) {
        #pragma unroll
        for (int m = 0; m < 4; ++m) {
            #pragma unroll
            for (int n = 0; n < 2; ++n) {
                #pragma unroll
                for (int j = 0; j < 4; ++j) {
                    const int gr = m0 + ((q >> 1) << 7) + wr * 64 + m * 16 + (fk << 2) + j;
                    const int gc = n0 + ((q & 1) << 7) + wc * 32 + n * 16 + frow;
                    float v = acc[q][m][n][j];
                    if (MODE == 0) {
                        v += bias[gc];
                        const int which = gc >> 10;
                        const int col = gc & 1023;
                        bf16* dst = which == 0 ? (bf16*)out0
                                  : which == 1 ? (bf16*)out1 : (bf16*)out2;
                        dst[(size_t)gr * 1024 + col] = __float2bfloat16(v);
                    } else if (MODE == 1) {
                        ((float*)out0)[(size_t)bz * (2048ull * 2048) +
                                       (size_t)gr * 2048 + gc] = v * 0.03125f;
                    } else {
                        ((float*)out0)[(size_t)gr * 1024 + gc] = v + bias[gc];
                    }
                }
            }
        }
    }
}

// ---------------------------------------------------------------------------
extern "C" void kernel_launch(void* const* d_in, const int* in_sizes, int n_in,
                              void* d_out, int out_size, void* d_ws, size_t ws_size,
                              hipStream_t stream) {
    const float* x      = (const float*)d_in[0];
    const float* w_qkv  = (const float*)d_in[1];
    const float* b_qkv  = (const float*)d_in[2];
    const float* w_proj = (const float*)d_in[3];
    const float* b_proj = (const float*)d_in[4];
    float* out = (float*)d_out;
    char* ws = (char*)d_ws;

    bf16* Xb = (bf16*)(ws);                        // 16 MB (later Vt)
    bf16* Wq = (bf16*)(ws + 16777216);             // 6 MB
    bf16* Wp = (bf16*)(ws + 23068672);             // 2 MB
    bf16* Qb = (bf16*)(ws + 25165824);             // 16 MB (later O)
    bf16* Kb = (bf16*)(ws + 41943040);             // 16 MB
    bf16* Vb = (bf16*)(ws + 58720256);             // 16 MB
    float* S = (float*)(ws + 75497472);            // 64 MB (P in-place)
    bf16* Vt = Xb;
    bf16* O  = Qb;

    hipLaunchKernelGGL(cvt_bf16, dim3(8192), dim3(256), 0, stream, x, Xb);
    hipLaunchKernelGGL(cvt_bf16, dim3(3072), dim3(256), 0, stream, w_qkv, Wq);
    hipLaunchKernelGGL(cvt_bf16, dim3(1024), dim3(256), 0, stream, w_proj, Wp);

    // QKV = Xb * Wq^T + b_qkv -> Q,K,V bf16   [256² 8-phase]
    gemm256<0><<<dim3(12, 32, 1), 512, 0, stream>>>(
        Xb, Wq, b_qkv, (void*)Qb, (void*)Kb, (void*)Vb);

    hipLaunchKernelGGL(transpose_v, dim3(32, 64, 4), dim3(32, 8), 0, stream, Vb, Vt);

    // S = Q * K^T / 32  (lower-triangle blocks)   [256² 8-phase]
    gemm256<1><<<dim3(8, 8, 4), 512, 0, stream>>>(
        Qb, Kb, (const float*)nullptr, (void*)S, nullptr, nullptr);

    hipLaunchKernelGGL(softmax_causal, dim3(8192), dim3(256), 0, stream, S);

    // O = P * V  (128² kernel, causal K clip)
    hipLaunchKernelGGL(gemm_bt, dim3(8, 16, 4), dim3(256), 0, stream,
        2, (const bf16*)S, 4096, (size_t)(2048ull * 4096), Vt, 2048,
        (size_t)(1024ull * 2048), 2048, (const float*)nullptr,
        (void*)O, (void*)nullptr, (void*)nullptr);

    // out = O * Wp^T + b_proj  (fp32)   [256² 8-phase]
    gemm256<3><<<dim3(4, 32, 1), 512, 0, stream>>>(
        O, Wp, b_proj, (void*)out, nullptr, nullptr);
}